// Round 1
// 216.083 us; speedup vs baseline: 1.0974x; 1.0974x over previous
//
#include <hip/hip_runtime.h>
#include <cmath>

#define NB 8
#define NA 49104
#define NM 50
#define NC 90
#define NBLK 192  // ceil(NA/256)

// ws layout (floats):
//   [0             .. NB*NBLK)    cls partials (neg sum + correction)
//   [NB*NBLK       .. 2*NB*NBLK)  reg partials
//   [2*NB*NBLK     .. 3*NB*NBLK)  num_pos partials
// All slots are overwritten every launch (no init required, atomics-free).

typedef float f32x4 __attribute__((ext_vector_type(4)));

__device__ __forceinline__ float clipc(float x) {
    return fminf(fmaxf(x, 1e-4f), 1.0f - 1e-4f);
}

__device__ __forceinline__ float negterm(float x) {
    const float c = clipc(x);
    return 0.75f * c * c * (-__logf(1.0f - c));
}

__device__ __forceinline__ float neg4(f32x4 v) {
    return (negterm(v.x) + negterm(v.y)) + (negterm(v.z) + negterm(v.w));
}

// One block = 256 consecutive anchors of one sample. Does assignment +
// smooth-L1 AND streams the block's own contiguous cls slice for the
// negative focal sum (single pass over the 141 MB tensor, coalesced).
__global__ __launch_bounds__(256) void fused_kernel(
    const float* __restrict__ boxes,      // [B,M,4] x1y1x2y2
    const int*   __restrict__ labels,     // [B,M], 0 = padding
    const float* __restrict__ regression, // [B,A,4]
    const float* __restrict__ cls,        // [B,A,C]
    const float* __restrict__ anchors,    // [A,4] y1x1y2x2
    float* __restrict__ ws) {
    __shared__ float4 sbox[NM];
    __shared__ float  sarea[NM];
    __shared__ int    slab[NM];
    __shared__ float  redc[4], redr[4], redn[4];

    const int b  = blockIdx.y;
    const int t  = threadIdx.x;
    const int a0 = blockIdx.x << 8;

    if (t < NM) {
        float4 bx = ((const float4*)boxes)[b * NM + t];
        const int l = labels[b * NM + t];
        float area = (bx.z - bx.x) * (bx.w - bx.y);
        if (l == 0) {
            // Invalid box: degenerate coords force inter=0 -> iou=0.
            // Output-equivalent to the reference's -1 mask (0 < 0.15 so
            // pos=false; ties at 0 only matter when !pos, where alab and
            // assigned are unused).
            bx.x = bx.y = bx.z = bx.w = 3e38f;
            area = 0.f;
        }
        sbox[t]  = bx;
        sarea[t] = area;
        slab[t]  = (l != 0) ? (l - 1) : 0;
    }
    __syncthreads();

    float corr = 0.f, regs = 0.f, npos = 0.f;
    const int a = a0 + t;
    if (a < NA) {
        const float4 an = ((const float4*)anchors)[a];
        const float ay1 = an.x, ax1 = an.y, ay2 = an.z, ax2 = an.w;
        const float aarea = (ay2 - ay1) * (ax2 - ax1);

        float best = -1.f;
        int arg = 0;
        for (int m = 0; m < NM; ++m) {
            const float4 bx = sbox[m];  // broadcast, conflict-free
            float iw = fminf(ax2, bx.z) - fmaxf(ax1, bx.x);
            float ih = fminf(ay2, bx.w) - fmaxf(ay1, bx.y);
            iw = fmaxf(iw, 0.f);
            ih = fmaxf(ih, 0.f);
            const float inter = iw * ih;
            const float ua = fmaxf(aarea + sarea[m] - inter, 1e-8f);
            const float iou = inter / ua;
            if (iou > best) { best = iou; arg = m; }  // first-occurrence
        }

        const bool big = sarea[arg] > 100.0f;
        const bool pos = big ? (best >= 0.5f) : (best >= 0.15f);
        if (pos) {
            npos = 1.f;
            const float4 bx = sbox[arg];
            const float aw = ax2 - ax1, ah = ay2 - ay1;
            const float acx = ax1 + 0.5f * aw, acy = ay1 + 0.5f * ah;
            const float gw0 = bx.z - bx.x, gh0 = bx.w - bx.y;
            const float gcx = bx.x + 0.5f * gw0, gcy = bx.y + 0.5f * gh0;
            const float gw = fmaxf(gw0, 1.f), gh = fmaxf(gh0, 1.f);
            const float4 r = ((const float4*)regression)[b * NA + a];
            const float d0 = fabsf((gcy - acy) / ah - r.x);
            const float d1 = fabsf((gcx - acx) / aw - r.y);
            const float d2 = fabsf(__logf(gh / ah) - r.z);
            const float d3 = fabsf(__logf(gw / aw) - r.w);
            regs  = (d0 <= 1.f / 9.f) ? 4.5f * d0 * d0 : d0 - (0.5f / 9.f);
            regs += (d1 <= 1.f / 9.f) ? 4.5f * d1 * d1 : d1 - (0.5f / 9.f);
            regs += (d2 <= 1.f / 9.f) ? 4.5f * d2 * d2 : d2 - (0.5f / 9.f);
            regs += (d3 <= 1.f / 9.f) ? 4.5f * d3 * d3 : d3 - (0.5f / 9.f);

            // replace neg term with pos term at (a, alab)
            const int alab = slab[arg];
            const float c = clipc(cls[((size_t)b * NA + a) * NC + alab]);
            const float omc = 1.f - c;
            corr = 0.25f * omc * omc * (-__logf(c)) -
                   0.75f * c * c * (-__logf(omc));
        }
    }

    // Streaming negative-term sum over this block's contiguous cls slice:
    // anchors [a0, aend) x 90 classes. Offsets/lengths are all 4-float
    // aligned (90*256 and 90*208 divisible by 4; base offsets div by 4).
    // 4-deep unrolled with independent accumulators so 4 16B loads are in
    // flight per wave per trip; non-temporal (read-once, no reuse).
    const int aend = (a0 + 256 < NA) ? a0 + 256 : NA;
    const int n4 = ((aend - a0) * NC) >> 2;
    const f32x4* p = (const f32x4*)(cls + ((size_t)b * NA + a0) * NC);
    float s0 = 0.f, s1 = 0.f, s2 = 0.f, s3 = 0.f;
    const int kmain = n4 & ~1023;  // multiple of 4*256
    for (int i = t; i < kmain; i += 1024) {
        const f32x4 v0 = __builtin_nontemporal_load(p + i);
        const f32x4 v1 = __builtin_nontemporal_load(p + i + 256);
        const f32x4 v2 = __builtin_nontemporal_load(p + i + 512);
        const f32x4 v3 = __builtin_nontemporal_load(p + i + 768);
        s0 += neg4(v0);
        s1 += neg4(v1);
        s2 += neg4(v2);
        s3 += neg4(v3);
    }
    for (int i = kmain + t; i < n4; i += 256) {
        s0 += neg4(__builtin_nontemporal_load(p + i));
    }
    float c = ((s0 + s1) + (s2 + s3)) + corr;

    // Joint 3-value block reduction: one shuffle tree, one syncthreads.
    float r = regs, n = npos;
#pragma unroll
    for (int o = 32; o > 0; o >>= 1) {
        c += __shfl_down(c, o, 64);
        r += __shfl_down(r, o, 64);
        n += __shfl_down(n, o, 64);
    }
    const int wave = t >> 6;
    const int lane = t & 63;
    if (lane == 0) { redc[wave] = c; redr[wave] = r; redn[wave] = n; }
    __syncthreads();
    if (t == 0) {
        const int idx = b * NBLK + blockIdx.x;
        ws[idx]                 = redc[0] + redc[1] + redc[2] + redc[3];
        ws[NB * NBLK + idx]     = redr[0] + redr[1] + redr[2] + redr[3];
        ws[2 * NB * NBLK + idx] = redn[0] + redn[1] + redn[2] + redn[3];
    }
}

// 512 threads = 8 waves; wave b reduces sample b's 192 partials with a
// single shuffle tree (no serial per-sample loop, one __syncthreads).
__global__ __launch_bounds__(512) void finalize_kernel(
    const float* __restrict__ ws, float* __restrict__ out) {
    __shared__ float scl[NB], srl[NB];
    const int w    = threadIdx.x >> 6;  // sample index
    const int lane = threadIdx.x & 63;

    float vc = 0.f, vr = 0.f, vn = 0.f;
#pragma unroll
    for (int i = 0; i < NBLK; i += 64) {
        const int j = i + lane;
        vc += ws[w * NBLK + j];
        vr += ws[NB * NBLK + w * NBLK + j];
        vn += ws[2 * NB * NBLK + w * NBLK + j];
    }
#pragma unroll
    for (int o = 32; o > 0; o >>= 1) {
        vc += __shfl_down(vc, o, 64);
        vr += __shfl_down(vr, o, 64);
        vn += __shfl_down(vn, o, 64);
    }
    if (lane == 0) {
        scl[w] = vc / fmaxf(vn, 1.f);
        srl[w] = (vn > 0.f) ? vr / (vn * 4.f) : 0.f;
    }
    __syncthreads();
    if (threadIdx.x == 0) {
        float cl = 0.f, rl = 0.f;
#pragma unroll
        for (int b = 0; b < NB; ++b) { cl += scl[b]; rl += srl[b]; }
        out[0] = cl / (float)NB;
        out[1] = rl / (float)NB * 50.f;
    }
}

extern "C" void kernel_launch(void* const* d_in, const int* in_sizes, int n_in,
                              void* d_out, int out_size, void* d_ws,
                              size_t ws_size, hipStream_t stream) {
    const float* boxes      = (const float*)d_in[0];  // [B,M,4] f32
    const int*   labels     = (const int*)d_in[1];    // [B,M] i32
    const float* regression = (const float*)d_in[2];  // [B,A,4] f32
    const float* cls        = (const float*)d_in[3];  // [B,A,C] f32
    const float* anchors    = (const float*)d_in[4];  // [1,A,4] f32
    float* out = (float*)d_out;
    float* ws  = (float*)d_ws;

    dim3 g(NBLK, NB);  // 1536 blocks, 6/CU, 24 waves/CU
    fused_kernel<<<g, 256, 0, stream>>>(boxes, labels, regression, cls,
                                        anchors, ws);
    finalize_kernel<<<1, 512, 0, stream>>>(ws, out);
}